// Round 1
// 553.193 us; speedup vs baseline: 2.0258x; 2.0258x over previous
//
#include <hip/hip_runtime.h>

#define Bn 4
#define Cn 4096
#define Mn 2048
#define Hn 16
#define Dn 128
#define Sn 64

typedef float f4 __attribute__((ext_vector_type(4)));

// ---------------------------------------------------------------------------
// Kernel 1 v2: pos[b][h][c] = pw[h]*c + dot(x[b][c][:], W[h][:])
// Entire W (16x2048 f32 = 131 KB) staged in LDS once per block.
// Block = 1024 threads (16 waves), 32 rows; wave handles 2 rows x 16 heads
// (acc = 32 VGPRs -> no spill). x streamed once with depth-1 float4 prefetch.
// Cross-lane reduction: in-register pairwise shfl tree (no LDS scratch).
// pos written coalesced via a small LDS gather buffer.
// ---------------------------------------------------------------------------
__global__ __launch_bounds__(1024, 4) void pos_kernel(
    const float* __restrict__ x,    // [B][C][M]
    const float* __restrict__ W,    // [H][M]
    const float* __restrict__ pw,   // [H]
    float* __restrict__ pos)        // [B][H][C]
{
    __shared__ __align__(16) float Wl[Hn * Mn];   // 131072 B
    __shared__ float posbuf[Hn][33];              // 2112 B, stride 33

    const int t = threadIdx.x;

    // ---- stage W into LDS: 8192 float4s, 8 per thread ----
    const float4* W4  = (const float4*)W;
    float4*       Wl4 = (float4*)Wl;
#pragma unroll
    for (int kk = 0; kk < 8; ++kk)
        Wl4[kk * 1024 + t] = W4[kk * 1024 + t];
    __syncthreads();

    const int wid  = t >> 6;
    const int lane = t & 63;
    const int row0 = blockIdx.x * 32;       // 512 blocks x 32 rows = 16384 rows
    const int b    = row0 >> 12;            // / 4096 (32 | 4096 -> no b crossing)
    const int c0   = row0 & 4095;
    const int r0   = row0 + wid * 2;        // this wave's first row

    const float4* x4 = (const float4*)x;
    const size_t  xb = (size_t)r0 * (Mn / 4);

    float acc0[16], acc1[16];
#pragma unroll
    for (int h = 0; h < Hn; ++h) { acc0[h] = 0.0f; acc1[h] = 0.0f; }

    // depth-1 prefetch of the two rows' float4 chunks
    float4 xa = x4[xb + lane];
    float4 xc = x4[xb + 512 + lane];
#pragma unroll
    for (int j = 0; j < 8; ++j) {
        float4 na, nc;
        if (j < 7) {
            na = x4[xb + (j + 1) * 64 + lane];
            nc = x4[xb + 512 + (j + 1) * 64 + lane];
        }
#pragma unroll
        for (int h = 0; h < Hn; ++h) {
            const float4 wv = Wl4[h * 512 + j * 64 + lane];
            acc0[h] += xa.x * wv.x; acc0[h] += xa.y * wv.y;
            acc0[h] += xa.z * wv.z; acc0[h] += xa.w * wv.w;
            acc1[h] += xc.x * wv.x; acc1[h] += xc.y * wv.y;
            acc1[h] += xc.z * wv.z; acc1[h] += xc.w * wv.w;
        }
        if (j < 7) { xa = na; xc = nc; }
    }

    // ---- in-register pairwise tree: after 5 stages + cross-half add,
    //      lane l holds the full 64-lane sum of value v = l & 31,
    //      where v = r*16 + h  (r in {0,1}) ----
    float vals[32];
#pragma unroll
    for (int h = 0; h < Hn; ++h) { vals[h] = acc0[h]; vals[16 + h] = acc1[h]; }

#pragma unroll
    for (int s = 0; s < 5; ++s) {
        const int m = 1 << s;
        const int nout = 16 >> s;
        const bool up = (lane & m) != 0;
#pragma unroll
        for (int k = 0; k < 16; ++k) {
            if (k < nout) {
                float a = vals[2 * k], bb = vals[2 * k + 1];
                float mine = up ? bb : a;
                float oth  = up ? a  : bb;
                vals[k] = mine + __shfl_xor(oth, m);
            }
        }
    }
    const float tot = vals[0] + __shfl_xor(vals[0], 32);

    if (lane < 32) {
        const int h = lane & 15;
        const int r = (lane >> 4) & 1;
        posbuf[h][wid * 2 + r] = tot;
    }
    __syncthreads();

    // coalesced pos write: 32 consecutive c per head
    if (t < 512) {
        const int h  = t >> 5;
        const int cc = t & 31;
        const int c  = c0 + cc;
        pos[((size_t)(b * Hn + h)) * Cn + c] = pw[h] * (float)c + posbuf[h][cc];
    }
}

// ---------------------------------------------------------------------------
// Kernel 2: rotate q and k. One thread per float4 = 2 (p0,p1) pairs.
// angle = pos * theta[s]; sin/cos via revolutions + fract + hw v_sin/v_cos.
// out stores are nontemporal (written once, never read) to keep L2/L3 clean.
// ---------------------------------------------------------------------------
__global__ __launch_bounds__(256) void rot_kernel(
    const float* __restrict__ q,
    const float* __restrict__ k,
    const float* __restrict__ theta,   // [S]
    const float* __restrict__ pos,     // [B*H*C]
    float* __restrict__ out)           // [2][B*H*C][D]
{
    const size_t tid = (size_t)blockIdx.x * 256 + threadIdx.x;  // over B*H*C*32
    const int sp = (int)(tid & 31);            // float4 index within row
    const size_t row = tid >> 5;

    const float p = pos[row];
    const float2 th = ((const float2*)theta)[sp];

    constexpr float inv2pi = 0.15915494309189535f;
    float r0 = p * th.x * inv2pi;
    float r1 = p * th.y * inv2pi;
    r0 = r0 - floorf(r0);
    r1 = r1 - floorf(r1);
    const float cs0 = __builtin_amdgcn_cosf(r0);
    const float sn0 = __builtin_amdgcn_sinf(r0);
    const float cs1 = __builtin_amdgcn_cosf(r1);
    const float sn1 = __builtin_amdgcn_sinf(r1);

    const f4* q4 = (const f4*)q;
    const f4* k4 = (const f4*)k;
    f4* o4 = (f4*)out;
    const size_t idx = row * 32 + sp;
    const size_t half = (size_t)Bn * Hn * Cn * 32;

    const f4 qv = q4[idx];
    f4 ov;
    ov.x = cs0 * qv.x - sn0 * qv.y;
    ov.y = sn0 * qv.x + cs0 * qv.y;
    ov.z = cs1 * qv.z - sn1 * qv.w;
    ov.w = sn1 * qv.z + cs1 * qv.w;
    __builtin_nontemporal_store(ov, o4 + idx);

    const f4 kv = k4[idx];
    f4 ok;
    ok.x = cs0 * kv.x - sn0 * kv.y;
    ok.y = sn0 * kv.x + cs0 * kv.y;
    ok.z = cs1 * kv.z - sn1 * kv.w;
    ok.w = sn1 * kv.z + cs1 * kv.w;
    __builtin_nontemporal_store(ok, o4 + idx + half);
}

extern "C" void kernel_launch(void* const* d_in, const int* in_sizes, int n_in,
                              void* d_out, int out_size, void* d_ws, size_t ws_size,
                              hipStream_t stream) {
    const float* x     = (const float*)d_in[0];  // [B,C,M]
    const float* q     = (const float*)d_in[1];  // [B,H,C,D]
    const float* k     = (const float*)d_in[2];  // [B,H,C,D]
    const float* W     = (const float*)d_in[3];  // [H,M]
    const float* pw    = (const float*)d_in[4];  // [H]
    const float* theta = (const float*)d_in[5];  // [S]
    float* out = (float*)d_out;
    float* pos = (float*)d_ws;                   // B*H*C floats = 1 MB

    // Kernel 1: 512 blocks x 1024 threads, 32 rows each
    pos_kernel<<<512, 1024, 0, stream>>>(x, W, pw, pos);

    // Kernel 2: B*H*C*32 threads = 8388608 -> 32768 blocks of 256
    rot_kernel<<<32768, 256, 0, stream>>>(q, k, theta, pos, out);
}

// Round 2
// 526.101 us; speedup vs baseline: 2.1301x; 1.0515x over previous
//
#include <hip/hip_runtime.h>

#define Bn 4
#define Cn 4096
#define Mn 2048
#define Hn 16
#define Dn 128
#define Sn 64

typedef float f4 __attribute__((ext_vector_type(4)));

// ---------------------------------------------------------------------------
// Kernel 1 v3: pos[b][h][c] = pw[h]*c + dot(x[b][c][:], W[h][:])
// Entire W (16x2048 f32 = 131 KB) staged in LDS once per block, stored
// permuted as [j][h][lane] (j = M-chunk) so inner-loop ds_read offsets fit
// the 16-bit immediate.
// Block = 1024 threads (16 waves), 64 rows; wave handles 4 rows x 16 heads.
// Grid = 256 blocks -> exactly 1 block/CU, ONE round (no serialized 2nd block).
// One W float4 read feeds 4 rows (16 FMA) -> LDS traffic halved vs v2.
// Cross-lane reduction: 6-stage in-register pairwise shfl tree
// (64 values -> lane l holds full sum of value l, l = r*16 + h).
// pos written coalesced via small LDS gather buffer.
// ---------------------------------------------------------------------------
__global__ __launch_bounds__(1024, 4) void pos_kernel(
    const float* __restrict__ x,    // [B][C][M]
    const float* __restrict__ W,    // [H][M]
    const float* __restrict__ pw,   // [H]
    float* __restrict__ pos)        // [B][H][C]
{
    __shared__ __align__(16) float Wl[Hn * Mn];   // 131072 B, layout [j][h][lane] in float4
    __shared__ float posbuf[Hn][65];              // 4160 B

    const int t = threadIdx.x;

    // ---- stage W into LDS, permuted [j][h][lane] ----
    const float4* W4  = (const float4*)W;
    float4*       Wl4 = (float4*)Wl;
#pragma unroll
    for (int kk = 0; kk < 8; ++kk) {
        const int idx = kk * 1024 + t;       // linear float4 index into W
        const int h   = idx >> 9;            // / 512
        const int m4  = idx & 511;
        const int j   = m4 >> 6;
        const int ln  = m4 & 63;
        Wl4[(j * 16 + h) * 64 + ln] = W4[idx];
    }
    __syncthreads();

    const int wid  = t >> 6;
    const int lane = t & 63;
    const int row0 = blockIdx.x * 64;       // 256 blocks x 64 rows = 16384 rows
    const int b    = row0 >> 12;            // 64 | 4096 -> no b crossing
    const int c0   = row0 & 4095;
    const int r0   = row0 + wid * 4;        // this wave's first row

    const float4* x4 = (const float4*)x;
    const size_t  xb = (size_t)r0 * (Mn / 4);

    float acc[4][16];
#pragma unroll
    for (int r = 0; r < 4; ++r)
#pragma unroll
        for (int h = 0; h < Hn; ++h) acc[r][h] = 0.0f;

    // depth-1 prefetch of the four rows' float4 chunks
    float4 cur[4];
#pragma unroll
    for (int r = 0; r < 4; ++r) cur[r] = x4[xb + (size_t)r * 512 + lane];

#pragma unroll
    for (int j = 0; j < 8; ++j) {
        float4 nxt[4];
        if (j < 7) {
#pragma unroll
            for (int r = 0; r < 4; ++r)
                nxt[r] = x4[xb + (size_t)r * 512 + (j + 1) * 64 + lane];
        }
        const float4* wj = Wl4 + j * 1024;   // [h][lane] slab, offsets < 16 KB
#pragma unroll
        for (int h = 0; h < Hn; ++h) {
            const float4 wv = wj[h * 64 + lane];
#pragma unroll
            for (int r = 0; r < 4; ++r) {
                acc[r][h] += cur[r].x * wv.x;
                acc[r][h] += cur[r].y * wv.y;
                acc[r][h] += cur[r].z * wv.z;
                acc[r][h] += cur[r].w * wv.w;
            }
        }
        if (j < 7) {
#pragma unroll
            for (int r = 0; r < 4; ++r) cur[r] = nxt[r];
        }
    }

    // ---- 6-stage in-register pairwise tree over 64 values ----
    // vals[v], v = r*16 + h; after 6 stages lane l holds full sum of value l.
    float vals[64];
#pragma unroll
    for (int r = 0; r < 4; ++r)
#pragma unroll
        for (int h = 0; h < Hn; ++h) vals[r * 16 + h] = acc[r][h];

#pragma unroll
    for (int s = 0; s < 6; ++s) {
        const int m = 1 << s;
        const int nout = 32 >> s;            // 32,16,8,4,2,1
        const bool up = (lane & m) != 0;
#pragma unroll
        for (int k = 0; k < 32; ++k) {
            if (k < nout) {
                float a = vals[2 * k], bb = vals[2 * k + 1];
                float mine = up ? bb : a;
                float oth  = up ? a  : bb;
                vals[k] = mine + __shfl_xor(oth, m);
            }
        }
    }
    // lane l: value v = l  ->  h = l & 15, r = l >> 4
    {
        const int h = lane & 15;
        const int r = lane >> 4;
        posbuf[h][wid * 4 + r] = vals[0];
    }
    __syncthreads();

    // coalesced pos write: 64 consecutive c per head, 16 heads x 64 = 1024 threads
    {
        const int h  = t >> 6;
        const int cc = t & 63;
        const int c  = c0 + cc;
        pos[((size_t)(b * Hn + h)) * Cn + c] = pw[h] * (float)c + posbuf[h][cc];
    }
}

// ---------------------------------------------------------------------------
// Kernel 2: rotate q and k. One thread per float4 = 2 (p0,p1) pairs.
// angle = pos * theta[s]; sin/cos via revolutions + fract + hw v_sin/v_cos.
// out stores are nontemporal (written once, never read) to keep L2/L3 clean.
// ---------------------------------------------------------------------------
__global__ __launch_bounds__(256) void rot_kernel(
    const float* __restrict__ q,
    const float* __restrict__ k,
    const float* __restrict__ theta,   // [S]
    const float* __restrict__ pos,     // [B*H*C]
    float* __restrict__ out)           // [2][B*H*C][D]
{
    const size_t tid = (size_t)blockIdx.x * 256 + threadIdx.x;  // over B*H*C*32
    const int sp = (int)(tid & 31);            // float4 index within row
    const size_t row = tid >> 5;

    const float p = pos[row];
    const float2 th = ((const float2*)theta)[sp];

    constexpr float inv2pi = 0.15915494309189535f;
    float r0 = p * th.x * inv2pi;
    float r1 = p * th.y * inv2pi;
    r0 = r0 - floorf(r0);
    r1 = r1 - floorf(r1);
    const float cs0 = __builtin_amdgcn_cosf(r0);
    const float sn0 = __builtin_amdgcn_sinf(r0);
    const float cs1 = __builtin_amdgcn_cosf(r1);
    const float sn1 = __builtin_amdgcn_sinf(r1);

    const f4* q4 = (const f4*)q;
    const f4* k4 = (const f4*)k;
    f4* o4 = (f4*)out;
    const size_t idx = row * 32 + sp;
    const size_t half = (size_t)Bn * Hn * Cn * 32;

    const f4 qv = q4[idx];
    f4 ov;
    ov.x = cs0 * qv.x - sn0 * qv.y;
    ov.y = sn0 * qv.x + cs0 * qv.y;
    ov.z = cs1 * qv.z - sn1 * qv.w;
    ov.w = sn1 * qv.z + cs1 * qv.w;
    __builtin_nontemporal_store(ov, o4 + idx);

    const f4 kv = k4[idx];
    f4 ok;
    ok.x = cs0 * kv.x - sn0 * kv.y;
    ok.y = sn0 * kv.x + cs0 * kv.y;
    ok.z = cs1 * kv.z - sn1 * kv.w;
    ok.w = sn1 * kv.z + cs1 * kv.w;
    __builtin_nontemporal_store(ok, o4 + idx + half);
}

extern "C" void kernel_launch(void* const* d_in, const int* in_sizes, int n_in,
                              void* d_out, int out_size, void* d_ws, size_t ws_size,
                              hipStream_t stream) {
    const float* x     = (const float*)d_in[0];  // [B,C,M]
    const float* q     = (const float*)d_in[1];  // [B,H,C,D]
    const float* k     = (const float*)d_in[2];  // [B,H,C,D]
    const float* W     = (const float*)d_in[3];  // [H,M]
    const float* pw    = (const float*)d_in[4];  // [H]
    const float* theta = (const float*)d_in[5];  // [S]
    float* out = (float*)d_out;
    float* pos = (float*)d_ws;                   // B*H*C floats = 1 MB

    // Kernel 1: 256 blocks x 1024 threads, 64 rows each (1 block/CU, one round)
    pos_kernel<<<256, 1024, 0, stream>>>(x, W, pw, pos);

    // Kernel 2: B*H*C*32 threads = 8388608 -> 32768 blocks of 256
    rot_kernel<<<32768, 256, 0, stream>>>(q, k, theta, pos, out);
}